// Round 8
// baseline (159.836 us; speedup 1.0000x reference)
//
#include <hip/hip_runtime.h>
#include <hip/hip_bf16.h>

// Problem constants
#define VOCAB 50000
#define ED    300
#define NT    16
#define BB    64
#define SS    512

#define LOG2E 1.4426950408889634f
#define LN2   0.6931471805599453f
#define WSTR  308   // padded W-transpose stride (2-way bank aliasing = free)

// ---------------------------------------------------------------------------
// Kernel 1: probs[row,:] = emb[text[row]] @ W + bias.  (round-4/7 verified)
// ---------------------------------------------------------------------------
__global__ __launch_bounds__(256) void probs_kernel(const int* __restrict__ text,
                                                    const float* __restrict__ emb,
                                                    const float* __restrict__ W,
                                                    const float* __restrict__ bias,
                                                    float* __restrict__ out_probs) {
  __shared__ float wt[NT * WSTR];  // wt[t*WSTR + d] = W[d*16 + t]

  const int tid = threadIdx.x;
  const int lane = tid & 63, wave = tid >> 6;
  const int r = lane >> 4, t = lane & 15;
  const int row = blockIdx.x * 16 + wave * 4 + r;

  for (int e = tid; e < ED * NT; e += 256) {
    int d = e >> 4, tt = e & 15;
    wt[tt * WSTR + d] = W[e];
  }

  const int tok = text[row];
  const float4* erow = (const float4*)(emb + (size_t)tok * ED);
  float acc = bias[t];

  float4 A[8];
#pragma unroll
  for (int i = 0; i < 8; ++i) A[i] = erow[i];

  __syncthreads();

  const float4* w4 = (const float4*)(wt + t * WSTR);
#pragma unroll
  for (int c = 0; c < 75; ++c) {
    float4 e = A[c & 7];
    if (c < 67) A[c & 7] = erow[c + 8];
    float4 w = w4[c];
    acc = fmaf(e.x, w.x, acc);
    acc = fmaf(e.y, w.y, acc);
    acc = fmaf(e.z, w.z, acc);
    acc = fmaf(e.w, w.w, acc);
  }
  out_probs[(size_t)row * NT + t] = acc;
}

// ---------------------------------------------------------------------------
// DPP helpers (controls HW-verified rounds 1-7). old = src (involutions, all
// lanes active -> old never observed).
//   0xB1 quad_perm lane^1, 0x4E lane^2, 0x1B lane^3,
//   0x141 row_half_mirror lane^7, 0x140 row_mirror lane^15.
// ---------------------------------------------------------------------------
template <int CTRL>
__device__ __forceinline__ float dppmov(float x) {
  int xi = __float_as_int(x);
  return __int_as_float(
      __builtin_amdgcn_update_dpp(xi, xi, CTRL, 0xF, 0xF, false));
}

// All lanes of a 16-lane row end with lam[k] = g_{j^k} (j = lane&15).
__device__ __forceinline__ void allgather16(float g, float lam[16]) {
  lam[0] = g;
  lam[1] = dppmov<0xB1>(g);
  lam[2] = dppmov<0x4E>(g);
  lam[3] = dppmov<0x1B>(g);
  float h = dppmov<0x141>(g);   // j^7
  lam[7] = h;
  lam[6] = dppmov<0xB1>(h);
  lam[5] = dppmov<0x4E>(h);
  lam[4] = dppmov<0x1B>(h);
  float m = dppmov<0x140>(g);   // j^15
  lam[15] = m;
  lam[14] = dppmov<0xB1>(m);
  lam[13] = dppmov<0x4E>(m);
  lam[12] = dppmov<0x1B>(m);
  float c = dppmov<0x141>(m);   // j^8
  lam[8] = c;
  lam[9]  = dppmov<0xB1>(c);
  lam[10] = dppmov<0x4E>(c);
  lam[11] = dppmov<0x1B>(c);
}

// ---------------------------------------------------------------------------
// One step of the linear recurrence on a 16-lane row (intrinsic form of the
// round-3..7 verified asm; same math, compiler-schedulable so multiple
// independent calls interleave for ILP):
//   out_j = (sum_k in_{j^k} * E[k]_j) * pe_j
// ---------------------------------------------------------------------------
__device__ __forceinline__ float crf_step_c(float g, float pe, const float E[16]) {
  float h = dppmov<0x141>(g);   // g_{j^7}
  float m = dppmov<0x140>(g);   // g_{j^15}
  float c = dppmov<0x141>(m);   // g_{j^8}
  float s0 = fmaf(dppmov<0x1B>(g), E[3],
             fmaf(dppmov<0x4E>(g), E[2], fmaf(dppmov<0xB1>(g), E[1], g * E[0])));
  float s1 = fmaf(dppmov<0x1B>(h), E[4],
             fmaf(dppmov<0x4E>(h), E[5], fmaf(dppmov<0xB1>(h), E[6], h * E[7])));
  float s2 = fmaf(dppmov<0x1B>(m), E[12],
             fmaf(dppmov<0x4E>(m), E[13], fmaf(dppmov<0xB1>(m), E[14], m * E[15])));
  float s3 = fmaf(dppmov<0x1B>(c), E[11],
             fmaf(dppmov<0x4E>(c), E[10], fmaf(dppmov<0xB1>(c), E[9], c * E[8])));
  return ((s0 + s1) + (s2 + s3)) * pe;
}

// ---------------------------------------------------------------------------
// Kernel 2: lens + scores + CRF log-likelihood via SEGMENTED MATRIX SCAN.
// One batch per block, 1024 threads = 16 waves.
//   alpha_s = alpha_{s-1} · A_s,  A_s[k][j] = E[k][j]*pe_s[j]  (E scaled 2^-5)
// Wave w computes P_w = prod of A_s over its 32-step segment, in matrix form:
// lane j of 16-lane row r holds P[i][j] for i in {4r..4r+3} (regs p0..p3);
// each step = 4 independent crf_step_c calls (ILP hides DPP latency).
// E scaled 2^-5 keeps 32-step products within 2^+-45 -> no intra-segment
// renorm; the exact 5*T scale is restored at the end (round-7 verified).
// Wave 0 then folds alpha0 through P_0..P_15 (allgather16 + conflict-free
// LDS reads), renormalizing each fold into K2.
// ---------------------------------------------------------------------------
__global__ __launch_bounds__(1024, 4) void crf_kernel(
    const int* __restrict__ text, const int* __restrict__ tags,
    const float* __restrict__ trans, const float* __restrict__ probs,
    float* __restrict__ out_lens, float* __restrict__ out_ll) {
  __shared__ float lps[SS * NT];    // probs * LOG2E (32 KB)
  __shared__ float pw[16 * 256];    // 16 segment matrices (16 KB)
  __shared__ int tgs[SS];
  __shared__ float trs[256];
  __shared__ float red_su[16], red_sb[16];
  __shared__ int red_cnt[16];

  const int tid = threadIdx.x;
  const int wave = tid >> 6, lane = tid & 63;
  const int j = lane & 15, row16 = (lane >> 4) & 3;
  const int b = blockIdx.x;

  // ---- stage (coalesced, 1024 threads) ----
  {
    const float4* p4 = (const float4*)(probs + (size_t)b * SS * NT);
    float4* l4 = (float4*)lps;
#pragma unroll
    for (int i = 0; i < 2; ++i) {
      float4 v = p4[tid + 1024 * i];
      v.x *= LOG2E; v.y *= LOG2E; v.z *= LOG2E; v.w *= LOG2E;
      l4[tid + 1024 * i] = v;
    }
    if (tid < 128) ((int4*)tgs)[tid] = ((const int4*)(tags + b * SS))[tid];
    if (tid < 256) trs[tid] = trans[tid];
  }
  __syncthreads();

  // ---- lens: sharded over tid<512, block-reduced ----
  int cpart = 0;
  if (tid < SS) cpart = (text[b * SS + tid] != 0) ? 1 : 0;
  for (int off = 32; off > 0; off >>= 1) cpart += __shfl_xor(cpart, off, 64);
  if (lane == 0) red_cnt[wave] = cpart;
  __syncthreads();
  int len = 0;
#pragma unroll
  for (int w = 0; w < 16; ++w) len += red_cnt[w];
  if (tid == 0) out_lens[b] = (float)len;

  // ---- phase A partials: s = tid ----
  float su = 0.f, sb = 0.f;
  if (tid < SS && tid < len) {
    int t1 = tgs[tid];
    su = lps[tid * NT + t1];
    if (tid >= 1) sb = trs[tgs[tid - 1] * 16 + t1];
  }
  for (int off = 32; off > 0; off >>= 1) su += __shfl_xor(su, off, 64);
  for (int off = 32; off > 0; off >>= 1) sb += __shfl_xor(sb, off, 64);
  if (lane == 0) { red_su[wave] = su; red_sb[wave] = sb; }

  // ---- E[k] = exp(trans[j^k, j]) * 2^-5 ----
  float E[16];
#pragma unroll
  for (int k = 0; k < 16; ++k) E[k] = __expf(trs[((j ^ k) << 4) + j]) * 0.03125f;

  // ---- segment product: wave w covers s in [1+32w, min(1+32w+32, len)) ----
  const int s_start = 1 + 32 * wave;
  int nst = len - s_start;
  nst = (nst < 0) ? 0 : ((nst > 32) ? 32 : nst);

  // P = I : lane j, row16=r, regs m=0..3 hold P[4r+m][j]
  float p0 = (j == 4 * row16 + 0) ? 1.f : 0.f;
  float p1 = (j == 4 * row16 + 1) ? 1.f : 0.f;
  float p2 = (j == 4 * row16 + 2) ? 1.f : 0.f;
  float p3 = (j == 4 * row16 + 3) ? 1.f : 0.f;

#pragma unroll 4
  for (int c = 0; c < nst; ++c) {
    float pe = exp2f(lps[(s_start + c) * NT + j]);
    p0 = crf_step_c(p0, pe, E);
    p1 = crf_step_c(p1, pe, E);
    p2 = crf_step_c(p2, pe, E);
    p3 = crf_step_c(p3, pe, E);
  }

  // store segment matrix: pw[wave*256 + i*16 + j] (conflict-free)
  {
    float* dst = pw + wave * 256;
    dst[(4 * row16 + 0) * 16 + j] = p0;
    dst[(4 * row16 + 1) * 16 + j] = p1;
    dst[(4 * row16 + 2) * 16 + j] = p2;
    dst[(4 * row16 + 3) * 16 + j] = p3;
  }
  __syncthreads();

  if (wave != 0) return;

  // ---- fold: alpha0 through the 16 segment matrices ----
  float g = exp2f(lps[j]);  // alpha from step 0 (raw scale)
  float K2 = 0.f;
  const int T = (len > 0) ? len - 1 : 0;

  for (int w = 0; w < 16; ++w) {
    int n = len - (1 + 32 * w);
    if (n > 0) {  // segment non-empty (wave-uniform)
      float lam[16];
      allgather16(g, lam);
      const float* A = pw + w * 256;
      float acc = 0.f;
#pragma unroll
      for (int k = 0; k < 16; ++k) acc = fmaf(lam[k], A[((j ^ k) << 4) + j], acc);
      g = acc;
      // renorm into K2 (exact fold)
      float mx = g;
      mx = fmaxf(mx, dppmov<0xB1>(mx));
      mx = fmaxf(mx, dppmov<0x4E>(mx));
      mx = fmaxf(mx, dppmov<0x141>(mx));
      mx = fmaxf(mx, dppmov<0x140>(mx));
      float rr = 1.0f / mx;
      K2 -= __log2f(rr);
      g *= rr;
    }
  }

  // ---- final logsumexp; +5*T undoes the E scaling; + scores ----
  float x = g;
  x += dppmov<0xB1>(x);
  x += dppmov<0x4E>(x);
  x += dppmov<0x141>(x);
  x += dppmov<0x140>(x);

  float su_t = 0.f, sb_t = 0.f;
#pragma unroll
  for (int w = 0; w < 16; ++w) { su_t += red_su[w]; sb_t += red_sb[w]; }
  float sc = fmaf(su_t, LN2, sb_t);

  float log_norm = LN2 * (K2 + 5.0f * (float)T + __log2f(x));
  if (lane == 0) out_ll[b] = sc - log_norm;
}

// ---------------------------------------------------------------------------
extern "C" void kernel_launch(void* const* d_in, const int* in_sizes, int n_in,
                              void* d_out, int out_size, void* d_ws, size_t ws_size,
                              hipStream_t stream) {
  const int* text = (const int*)d_in[0];
  const int* tags = (const int*)d_in[1];
  const float* emb = (const float*)d_in[2];
  const float* W = (const float*)d_in[3];
  const float* bias = (const float*)d_in[4];
  const float* trans = (const float*)d_in[5];

  float* out = (float*)d_out;
  float* out_probs = out;                   // 64*512*16
  float* out_lens = out + BB * SS * NT;     // 64
  float* out_ll = out + BB * SS * NT + BB;  // 64

  probs_kernel<<<(BB * SS) / 16, 256, 0, stream>>>(text, emb, W, bias, out_probs);
  crf_kernel<<<BB, 1024, 0, stream>>>(text, tags, trans, out_probs, out_lens, out_ll);
}

// Round 9
// 152.096 us; speedup vs baseline: 1.0509x; 1.0509x over previous
//
#include <hip/hip_runtime.h>
#include <hip/hip_bf16.h>

// Problem constants
#define VOCAB 50000
#define ED    300
#define NT    16
#define BB    64
#define SS    512

#define LOG2E 1.4426950408889634f
#define LN2   0.6931471805599453f
#define WSTR  308   // padded W-transpose stride (2-way bank aliasing = free)

// ---------------------------------------------------------------------------
// Kernel 1: probs[row,:] = emb[text[row]] @ W + bias.  (round-4/7 verified)
// ---------------------------------------------------------------------------
__global__ __launch_bounds__(256) void probs_kernel(const int* __restrict__ text,
                                                    const float* __restrict__ emb,
                                                    const float* __restrict__ W,
                                                    const float* __restrict__ bias,
                                                    float* __restrict__ out_probs) {
  __shared__ float wt[NT * WSTR];  // wt[t*WSTR + d] = W[d*16 + t]

  const int tid = threadIdx.x;
  const int lane = tid & 63, wave = tid >> 6;
  const int r = lane >> 4, t = lane & 15;
  const int row = blockIdx.x * 16 + wave * 4 + r;

  for (int e = tid; e < ED * NT; e += 256) {
    int d = e >> 4, tt = e & 15;
    wt[tt * WSTR + d] = W[e];
  }

  const int tok = text[row];
  const float4* erow = (const float4*)(emb + (size_t)tok * ED);
  float acc = bias[t];

  float4 A[8];
#pragma unroll
  for (int i = 0; i < 8; ++i) A[i] = erow[i];

  __syncthreads();

  const float4* w4 = (const float4*)(wt + t * WSTR);
#pragma unroll
  for (int c = 0; c < 75; ++c) {
    float4 e = A[c & 7];
    if (c < 67) A[c & 7] = erow[c + 8];
    float4 w = w4[c];
    acc = fmaf(e.x, w.x, acc);
    acc = fmaf(e.y, w.y, acc);
    acc = fmaf(e.z, w.z, acc);
    acc = fmaf(e.w, w.w, acc);
  }
  out_probs[(size_t)row * NT + t] = acc;
}

// ---------------------------------------------------------------------------
// DPP helpers (controls HW-verified rounds 1-8).
// ---------------------------------------------------------------------------
template <int CTRL>
__device__ __forceinline__ float dppmov(float x) {
  int xi = __float_as_int(x);
  return __int_as_float(
      __builtin_amdgcn_update_dpp(xi, xi, CTRL, 0xF, 0xF, false));
}

// ---------------------------------------------------------------------------
// One CRF forward step — INTERLEAVED fused DPP matvec.
//   gn_j = (sum_k alpha_{j^k} * E[k]_j) * pe_j,  E[k]_j ~ exp(trans[j^k, j])
// Same math as the round-3..8 verified block; the 4 accumulator chains
// (gn,a1,a2,a3) are now interleaved level-by-level so each fmac's ~4-5cyc
// latency is hidden by the other 3 chains' issue slots.
// Hazard audit (DPP reads need >=2 instr after the source's VALU write):
//   g: written by previous step's final v_mul -> s_nop 1 + h/m movs cover.
//   h: written inst1, first DPP-read inst9  (8 apart).
//   m: written inst2, first DPP-read inst11 (9 apart); c=dpp(m) at inst5 (3).
//   c: written inst5, first DPP-read inst12 (7 apart).
// Accumulator RAW (plain VALU, HW-interlocked): each fmac is 4 instrs after
// the previous write of the same accumulator.
// ---------------------------------------------------------------------------
__device__ __forceinline__ float crf_step(float g, float pe, const float E[16]) {
  float gn, h, m, c, a1, a2, a3;
  asm("s_nop 1\n\t"
      "v_mov_b32_dpp %[h], %[g] row_half_mirror row_mask:0xf bank_mask:0xf\n\t"
      "v_mov_b32_dpp %[m], %[g] row_mirror row_mask:0xf bank_mask:0xf\n\t"
      "v_mul_f32 %[gn], %[g], %[e0]\n\t"
      "v_mul_f32 %[a1], %[h], %[e7]\n\t"
      "v_mov_b32_dpp %[c], %[m] row_half_mirror row_mask:0xf bank_mask:0xf\n\t"
      "v_mul_f32 %[a2], %[m], %[e15]\n\t"
      "v_mul_f32 %[a3], %[c], %[e8]\n\t"
      "v_fmac_f32_dpp %[gn], %[g], %[e1] quad_perm:[1,0,3,2] row_mask:0xf bank_mask:0xf\n\t"
      "v_fmac_f32_dpp %[a1], %[h], %[e6] quad_perm:[1,0,3,2] row_mask:0xf bank_mask:0xf\n\t"
      "v_fmac_f32_dpp %[a2], %[m], %[e14] quad_perm:[1,0,3,2] row_mask:0xf bank_mask:0xf\n\t"
      "v_fmac_f32_dpp %[a3], %[c], %[e9] quad_perm:[1,0,3,2] row_mask:0xf bank_mask:0xf\n\t"
      "v_fmac_f32_dpp %[gn], %[g], %[e2] quad_perm:[2,3,0,1] row_mask:0xf bank_mask:0xf\n\t"
      "v_fmac_f32_dpp %[a1], %[h], %[e5] quad_perm:[2,3,0,1] row_mask:0xf bank_mask:0xf\n\t"
      "v_fmac_f32_dpp %[a2], %[m], %[e13] quad_perm:[2,3,0,1] row_mask:0xf bank_mask:0xf\n\t"
      "v_fmac_f32_dpp %[a3], %[c], %[e10] quad_perm:[2,3,0,1] row_mask:0xf bank_mask:0xf\n\t"
      "v_fmac_f32_dpp %[gn], %[g], %[e3] quad_perm:[3,2,1,0] row_mask:0xf bank_mask:0xf\n\t"
      "v_fmac_f32_dpp %[a1], %[h], %[e4] quad_perm:[3,2,1,0] row_mask:0xf bank_mask:0xf\n\t"
      "v_fmac_f32_dpp %[a2], %[m], %[e12] quad_perm:[3,2,1,0] row_mask:0xf bank_mask:0xf\n\t"
      "v_fmac_f32_dpp %[a3], %[c], %[e11] quad_perm:[3,2,1,0] row_mask:0xf bank_mask:0xf\n\t"
      "v_add_f32 %[gn], %[gn], %[a1]\n\t"
      "v_add_f32 %[a2], %[a2], %[a3]\n\t"
      "v_add_f32 %[gn], %[gn], %[a2]\n\t"
      "v_mul_f32 %[gn], %[gn], %[pe]"
      : [gn] "=&v"(gn), [h] "=&v"(h), [m] "=&v"(m), [c] "=&v"(c),
        [a1] "=&v"(a1), [a2] "=&v"(a2), [a3] "=&v"(a3)
      : [g] "v"(g), [pe] "v"(pe),
        [e0] "v"(E[0]), [e1] "v"(E[1]), [e2] "v"(E[2]), [e3] "v"(E[3]),
        [e4] "v"(E[4]), [e5] "v"(E[5]), [e6] "v"(E[6]), [e7] "v"(E[7]),
        [e8] "v"(E[8]), [e9] "v"(E[9]), [e10] "v"(E[10]), [e11] "v"(E[11]),
        [e12] "v"(E[12]), [e13] "v"(E[13]), [e14] "v"(E[14]), [e15] "v"(E[15]));
  return gn;
}

// ---------------------------------------------------------------------------
// Kernel 2: lens + CRF log-likelihood (round-7 structure, verified).
// One batch/block, 64 threads. Scan in scaled-linear space; E pre-scaled 2^-5
// (renorm every 64 steps; 5*T folded back analytically). Steps s>=len are
// exact no-ops: skipped via dynamic trip count.
// ---------------------------------------------------------------------------
__global__ __launch_bounds__(64) void crf_kernel(const int* __restrict__ text,
                                                 const int* __restrict__ tags,
                                                 const float* __restrict__ trans,
                                                 const float* __restrict__ probs,
                                                 float* __restrict__ out_lens,
                                                 float* __restrict__ out_ll) {
  __shared__ float lps[(SS + 1) * NT];  // probs * LOG2E, +1 pad row
  __shared__ int tgs[SS];
  __shared__ float trs[256];

  const int tid = threadIdx.x;
  const int j = tid & 15;
  const int b = blockIdx.x;

  // ---- stage (coalesced), pre-scaling probs by log2e ----
  {
    const float4* p4 = (const float4*)(probs + (size_t)b * SS * NT);
    float4* l4 = (float4*)lps;
#pragma unroll
    for (int i = 0; i < 32; ++i) {
      float4 v = p4[tid + 64 * i];
      v.x *= LOG2E; v.y *= LOG2E; v.z *= LOG2E; v.w *= LOG2E;
      l4[tid + 64 * i] = v;
    }
    const int4* t4 = (const int4*)(tags + b * SS);
    int4* lt = (int4*)tgs;
#pragma unroll
    for (int i = 0; i < 2; ++i) lt[tid + 64 * i] = t4[tid + 64 * i];
    for (int i = tid; i < 256; i += 64) trs[i] = trans[i];
  }
  __syncthreads();

  // ---- lens (fused) ----
  const int* tx = text + b * SS;
  int cnt = 0;
#pragma unroll
  for (int k = 0; k < 8; ++k) cnt += (tx[tid + 64 * k] != 0) ? 1 : 0;
  for (int off = 32; off > 0; off >>= 1) cnt += __shfl_xor(cnt, off, 64);
  const int len = cnt;
  if (tid == 0) out_lens[b] = (float)len;

  // ---- phase A: unary + binary scores ----
  float su = 0.f, sb = 0.f;
#pragma unroll
  for (int it = 0; it < 8; ++it) {
    const int s = tid + 64 * it;
    if (s < len) {
      int t1 = tgs[s];
      su += lps[s * NT + t1];
      if (s >= 1) sb += trs[tgs[s - 1] * 16 + t1];
    }
  }
  float sc = fmaf(su, LN2, sb);
  for (int off = 32; off > 0; off >>= 1) sc += __shfl_xor(sc, off, 64);

  // ---- E[k] = exp(trans[j^k, j]) * 2^-5 (scale folded back via K2) ----
  float E[16];
#pragma unroll
  for (int k = 0; k < 16; ++k) E[k] = __expf(trs[((j ^ k) << 4) + j]) * 0.03125f;

  // ---- scan: s = 1 .. len-1 ----
  float g = exp2f(lps[j]);  // alpha from step 0
  float K2 = 0.f;

  const int T = (len > 0) ? len - 1 : 0;
  const int nfull = T >> 4;
  const int rem = T & 15;

  float raw[16];
#pragma unroll
  for (int c = 0; c < 16; ++c) raw[c] = lps[(1 + c) * NT + j];

  int s0 = 1;
  for (int blk = 0; blk < nfull; ++blk) {
#pragma unroll
    for (int c = 0; c < 16; ++c) {
      float pe = exp2f(raw[c]);
      raw[c] = lps[(s0 + 16 + c) * NT + j];  // rows <= 512 (pad row)
      g = crf_step(g, pe, E);
    }
    // renorm every 4 chunks = 64 steps (per-step factor ~[0.4,1.8] after the
    // 2^-5 E scale -> worst 79-step span within 2^+-90 < fp32 range).
    if ((blk & 3) == 3) {
      float mx = g;
      mx = fmaxf(mx, dppmov<0xB1>(mx));
      mx = fmaxf(mx, dppmov<0x4E>(mx));
      mx = fmaxf(mx, dppmov<0x141>(mx));
      mx = fmaxf(mx, dppmov<0x140>(mx));
      float rr = 1.0f / mx;
      K2 -= __log2f(rr);
      g *= rr;
    }
    s0 += 16;
  }
  for (int c = 0; c < rem; ++c) {
    float pe = exp2f(raw[c]);
    g = crf_step(g, pe, E);
  }

  // ---- final logsumexp; +5*T undoes the E scaling ----
  float x = g;
  x += dppmov<0xB1>(x);
  x += dppmov<0x4E>(x);
  x += dppmov<0x141>(x);
  x += dppmov<0x140>(x);
  float log_norm = LN2 * (K2 + 5.0f * (float)T + __log2f(x));
  if (tid == 0) out_ll[b] = sc - log_norm;
}

// ---------------------------------------------------------------------------
extern "C" void kernel_launch(void* const* d_in, const int* in_sizes, int n_in,
                              void* d_out, int out_size, void* d_ws, size_t ws_size,
                              hipStream_t stream) {
  const int* text = (const int*)d_in[0];
  const int* tags = (const int*)d_in[1];
  const float* emb = (const float*)d_in[2];
  const float* W = (const float*)d_in[3];
  const float* bias = (const float*)d_in[4];
  const float* trans = (const float*)d_in[5];

  float* out = (float*)d_out;
  float* out_probs = out;                   // 64*512*16
  float* out_lens = out + BB * SS * NT;     // 64
  float* out_ll = out + BB * SS * NT + BB;  // 64

  probs_kernel<<<(BB * SS) / 16, 256, 0, stream>>>(text, emb, W, bias, out_probs);
  crf_kernel<<<BB, 64, 0, stream>>>(text, tags, trans, out_probs, out_lens, out_ll);
}